// Round 5
// baseline (434.166 us; speedup 1.0000x reference)
//
#include <hip/hip_runtime.h>
#include <math.h>

// ToHyperSphere: x (B=65536, D=1024) fp32 -> out (B, D) fp32
// out[0]   = sqrt(sum x^2)                        (r)
// out[j]   = acos(x[j-1]/suffix_norm[j-1]), j=1..D-2
// out[D-1] = x[D-1] < 0 ? 2pi - phi[D-2] : phi[D-2]
// suffix_norm[j] = sqrt(sum_{k>=j} x[k]^2)
//
// ROUND-5: round-4 math (DPP suffix scan + poly acos, block-per-row,
// 1 float4/thread) wrapped in a PERSISTENT-BLOCK pipeline:
//  - grid = 2048 blocks (8/CU), each loops over 32 rows -> 32x fewer
//    workgroup launches.
//  - next row's float4 is loaded at loop top (register prefetch, ~full
//    iteration of latency-hiding; round 4 had zero MLP per thread).
//  - barrier = s_waitcnt lgkmcnt(0) + raw s_barrier (NOT __syncthreads,
//    which drains vmcnt(0): that would put the prefetch load AND the
//    previous row's store-acks on every row's critical path).
//  - LDS cross-wave slots parity-double-buffered (wave_tot[2][4]) so one
//    barrier per row suffices: reads@i are lgkm-drained before barrier@i+1,
//    and the next write to the same slot is @i+2, after barrier@i+1.

#define D_DIM 1024
#define TPB 256   // 4 waves per block, one row per iteration
#define NBLK 2048 // 8 blocks/CU * 256 CUs; 65536/2048 = 32 rows/block

typedef float v4f __attribute__((ext_vector_type(4)));

// DPP: value of (lane + N) within the 16-lane row, 0 past row end.
template <int CTRL>
__device__ __forceinline__ float dpp0(float x) {
    return __builtin_bit_cast(
        float, __builtin_amdgcn_update_dpp(0, __builtin_bit_cast(int, x),
                                           CTRL, 0xF, 0xF, true));
}

__device__ __forceinline__ float rdlane(float x, int l) {
    return __builtin_bit_cast(
        float, __builtin_amdgcn_readlane(__builtin_bit_cast(int, x), l));
}

// acos via Abramowitz&Stegun 4.4.46: acos(a) = sqrt(1-a)*poly(a), a in [0,1];
// acos(x) = pi - acos(-x) for x < 0.
__device__ __forceinline__ float fast_acos(float x) {
    float a = fabsf(x);
    float p = fmaf(a, -0.0012624911f, 0.0066700901f);
    p = fmaf(p, a, -0.0170881256f);
    p = fmaf(p, a, 0.0308918810f);
    p = fmaf(p, a, -0.0501743046f);
    p = fmaf(p, a, 0.0889789874f);
    p = fmaf(p, a, -0.2145988016f);
    p = fmaf(p, a, 1.5707963050f);
    float r = sqrtf(1.0f - a) * p;
    return x < 0.0f ? 3.14159274101257f - r : r;
}

__device__ __forceinline__ float ang(float num, float den) {
    float r = num * rsqrtf(den);
    r = fminf(1.0f, fmaxf(-1.0f, r));
    return fast_acos(r);
}

__global__ __launch_bounds__(TPB) void tohypersphere_kernel(
    const float* __restrict__ x, float* __restrict__ out, int n_rows) {
    const int t = threadIdx.x;
    const int lane = t & 63;
    const int wave = t >> 6;
    const int r16 = lane >> 4;

    __shared__ float wave_tot[2][4];  // parity-double-buffered
    __shared__ float edge_xw[2][4];

    const int stride = gridDim.x;
    int row = blockIdx.x;
    if (row >= n_rows) return;  // uniform per block

    const float4* __restrict__ xp = (const float4*)x + t;
    v4f* __restrict__ op = (v4f*)out + t;

    // prime the pipeline
    float4 vc = xp[(size_t)row * (D_DIM / 4)];

    int p = 0;
    while (true) {
        const int nrow = row + stride;
        const bool more = (nrow < n_rows);  // uniform
        float4 vn;
        if (more) vn = xp[(size_t)nrow * (D_DIM / 4)];  // prefetch next row

        const float4 v = vc;
        // thread-local suffix sums of squares (elements 4t..4t+3)
        const float s3v = v.w * v.w;
        const float s2v = fmaf(v.z, v.z, s3v);
        const float s1v = fmaf(v.y, v.y, s2v);
        const float s0v = fmaf(v.x, v.x, s1v);

        // 16-lane-row inclusive suffix scan (unguarded DPP adds)
        float ts = s0v;
        ts += dpp0<0x101>(ts);  // row_shl:1
        ts += dpp0<0x102>(ts);  // row_shl:2
        ts += dpp0<0x104>(ts);  // row_shl:4
        ts += dpp0<0x108>(ts);  // row_shl:8

        // row totals (lanes 0,16,32,48) -> wave-uniform scalars
        const float R0 = rdlane(ts, 0);
        const float R1 = rdlane(ts, 16);
        const float R2 = rdlane(ts, 32);
        const float R3 = rdlane(ts, 48);

        float after_rows = 0.0f;
        if (r16 < 1) after_rows += R1;
        if (r16 < 2) after_rows += R2;
        if (r16 < 3) after_rows += R3;
        const float incl_wave = ts + after_rows;
        const float wtot = (R0 + R1) + (R2 + R3);

        if (lane == 0) wave_tot[p][wave] = wtot;
        if (lane == 63) edge_xw[p][wave] = v.w;

        // previous thread's last element x[4t-1] (intra-wave, pre-barrier)
        float xw_prev = __shfl_up(v.w, 1, 64);

        // LDS-producer fence + raw barrier: vmcnt NOT drained, so the vn
        // prefetch and last row's stores stay in flight across the barrier.
        asm volatile("s_waitcnt lgkmcnt(0)" ::: "memory");
        __builtin_amdgcn_s_barrier();
        __builtin_amdgcn_sched_barrier(0);  // pin ds_reads below the barrier

        float after_waves = 0.0f;
#pragma unroll
        for (int w = 1; w < 4; ++w)
            if (w > wave) after_waves += wave_tot[p][w];
        if (lane == 0 && wave > 0) xw_prev = edge_xw[p][wave - 1];

        const float incl = incl_wave + after_waves;  // suffix[4t]
        const float excl = incl - s0v;               // suffix after 4t+3

        float o0, o1, o2, o3;
        o1 = ang(v.x, incl);        // phi[4t]   -> out[4t+1]
        o2 = ang(v.y, s1v + excl);  // phi[4t+1] -> out[4t+2]
        o3 = ang(v.z, s2v + excl);  // phi[4t+2] -> out[4t+3]
        if (t == 0) {
            o0 = sqrtf(incl);       // r -> out[0]
        } else {
            // phi[4t-1]: suffix[4t-1] = x[4t-1]^2 + suffix[4t]
            o0 = ang(xw_prev, fmaf(xw_prev, xw_prev, incl));
        }
        if (t == TPB - 1 && v.w < 0.0f) {
            // out[D-1]: sign-adjusted phi[D-2]
            o3 = 6.283185307179586476f - o3;
        }

        v4f tv = {o0, o1, o2, o3};
        op[(size_t)row * (D_DIM / 4)] = tv;

        if (!more) break;
        row = nrow;
        vc = vn;
        p ^= 1;
    }
}

extern "C" void kernel_launch(void* const* d_in, const int* in_sizes, int n_in,
                              void* d_out, int out_size, void* d_ws, size_t ws_size,
                              hipStream_t stream) {
    const float* x = (const float*)d_in[0];
    float* out = (float*)d_out;
    const int B = in_sizes[0] / D_DIM;  // 65536
    const int grid = (B < NBLK) ? B : NBLK;
    tohypersphere_kernel<<<grid, TPB, 0, stream>>>(x, out, B);
}

// Round 6
// 425.976 us; speedup vs baseline: 1.0192x; 1.0192x over previous
//
#include <hip/hip_runtime.h>
#include <math.h>

// ToHyperSphere: x (B=65536, D=1024) fp32 -> out (B, D) fp32
// out[0]   = sqrt(sum x^2)                        (r)
// out[j]   = acos(x[j-1]/suffix_norm[j-1]), j=1..D-2
// out[D-1] = x[D-1] < 0 ? 2pi - phi[D-2] : phi[D-2]
// suffix_norm[j] = sqrt(sum_{k>=j} x[k]^2)
//
// ROUND-6: R4 structure (block-per-row, 1 float4/thread, DPP suffix scan,
// poly acos) extended to TWO ROWS PER BLOCK with the same 256 threads:
//  - each thread loads float4 from row 2b and 2b+1 back-to-back: MLP=2
//    (R4 had exactly one load per thread -> zero memory-level parallelism),
//    and the block touches 8KB contiguous.
//  - both rows' scans run interleaved (2x ILP in the latency-bound
//    DPP/readlane chain).
//  - ONE barrier serves both rows (R4 paid one barrier per row).
//  - no persistent loop: R5 showed persistent blocks REGRESS (151us vs
//    129us) -- the HW dispatcher beats a software loop + lockstep barrier.

#define D_DIM 1024
#define TPB 256  // 4 waves per block
#define ROWS 2   // rows per block

typedef float v4f __attribute__((ext_vector_type(4)));

// DPP: value of (lane + N) within the 16-lane row, 0 past row end.
template <int CTRL>
__device__ __forceinline__ float dpp0(float x) {
    return __builtin_bit_cast(
        float, __builtin_amdgcn_update_dpp(0, __builtin_bit_cast(int, x),
                                           CTRL, 0xF, 0xF, true));
}

__device__ __forceinline__ float rdlane(float x, int l) {
    return __builtin_bit_cast(
        float, __builtin_amdgcn_readlane(__builtin_bit_cast(int, x), l));
}

// acos via Abramowitz&Stegun 4.4.46: acos(a) = sqrt(1-a)*poly(a), a in [0,1];
// acos(x) = pi - acos(-x) for x < 0.
__device__ __forceinline__ float fast_acos(float x) {
    float a = fabsf(x);
    float p = fmaf(a, -0.0012624911f, 0.0066700901f);
    p = fmaf(p, a, -0.0170881256f);
    p = fmaf(p, a, 0.0308918810f);
    p = fmaf(p, a, -0.0501743046f);
    p = fmaf(p, a, 0.0889789874f);
    p = fmaf(p, a, -0.2145988016f);
    p = fmaf(p, a, 1.5707963050f);
    float r = sqrtf(1.0f - a) * p;
    return x < 0.0f ? 3.14159274101257f - r : r;
}

__device__ __forceinline__ float ang(float num, float den) {
    float r = num * rsqrtf(den);
    r = fminf(1.0f, fmaxf(-1.0f, r));
    return fast_acos(r);
}

__global__ __launch_bounds__(TPB) void tohypersphere_kernel(
    const float* __restrict__ x, float* __restrict__ out) {
    const int t = threadIdx.x;
    const int lane = t & 63;
    const int wave = t >> 6;
    const int r16 = lane >> 4;
    const size_t base = (size_t)blockIdx.x * (ROWS * D_DIM);

    // back-to-back independent loads: 2 rows, same chunk index t
    float4 v[ROWS];
#pragma unroll
    for (int r = 0; r < ROWS; ++r)
        v[r] = ((const float4*)(x + base + r * D_DIM))[t];

    // thread-local suffix sums of squares (elements 4t..4t+3), both rows
    float s1[ROWS], s2[ROWS], s0[ROWS];
#pragma unroll
    for (int r = 0; r < ROWS; ++r) {
        float s3 = v[r].w * v[r].w;
        s2[r] = fmaf(v[r].z, v[r].z, s3);
        s1[r] = fmaf(v[r].y, v[r].y, s2[r]);
        s0[r] = fmaf(v[r].x, v[r].x, s1[r]);
    }

    // 16-lane-row inclusive suffix scans, interleaved across rows
    float ts[ROWS];
#pragma unroll
    for (int r = 0; r < ROWS; ++r) ts[r] = s0[r];
#pragma unroll
    for (int r = 0; r < ROWS; ++r) ts[r] += dpp0<0x101>(ts[r]);  // +1
#pragma unroll
    for (int r = 0; r < ROWS; ++r) ts[r] += dpp0<0x102>(ts[r]);  // +2
#pragma unroll
    for (int r = 0; r < ROWS; ++r) ts[r] += dpp0<0x104>(ts[r]);  // +4
#pragma unroll
    for (int r = 0; r < ROWS; ++r) ts[r] += dpp0<0x108>(ts[r]);  // +8

    __shared__ float wave_tot[ROWS][4];
    __shared__ float edge_xw[ROWS][4];

    float incl_wave[ROWS], xw_prev[ROWS];
#pragma unroll
    for (int r = 0; r < ROWS; ++r) {
        const float R1 = rdlane(ts[r], 16);
        const float R2 = rdlane(ts[r], 32);
        const float R3 = rdlane(ts[r], 48);
        const float R0 = rdlane(ts[r], 0);
        float after_rows = 0.0f;
        if (r16 < 1) after_rows += R1;
        if (r16 < 2) after_rows += R2;
        if (r16 < 3) after_rows += R3;
        incl_wave[r] = ts[r] + after_rows;
        const float wtot = (R0 + R1) + (R2 + R3);
        if (lane == 0) wave_tot[r][wave] = wtot;
        if (lane == 63) edge_xw[r][wave] = v[r].w;
        xw_prev[r] = __shfl_up(v[r].w, 1, 64);  // intra-wave x[4t-1]
    }

    __syncthreads();  // one barrier for both rows

#pragma unroll
    for (int r = 0; r < ROWS; ++r) {
        float after_waves = 0.0f;
#pragma unroll
        for (int w = 1; w < 4; ++w)
            if (w > wave) after_waves += wave_tot[r][w];
        float xp = xw_prev[r];
        if (lane == 0 && wave > 0) xp = edge_xw[r][wave - 1];

        const float incl = incl_wave[r] + after_waves;  // suffix[4t]
        const float excl = incl - s0[r];                // suffix after 4t+3

        float o0, o1, o2, o3;
        o1 = ang(v[r].x, incl);        // phi[4t]   -> out[4t+1]
        o2 = ang(v[r].y, s1[r] + excl);// phi[4t+1] -> out[4t+2]
        o3 = ang(v[r].z, s2[r] + excl);// phi[4t+2] -> out[4t+3]
        if (t == 0) {
            o0 = sqrtf(incl);          // r -> out[0]
        } else {
            // phi[4t-1]: suffix[4t-1] = x[4t-1]^2 + suffix[4t]
            o0 = ang(xp, fmaf(xp, xp, incl));
        }
        if (t == TPB - 1 && v[r].w < 0.0f) {
            // out[D-1]: sign-adjusted phi[D-2]
            o3 = 6.283185307179586476f - o3;
        }

        v4f tv = {o0, o1, o2, o3};
        ((v4f*)(out + base + r * D_DIM))[t] = tv;
    }
}

extern "C" void kernel_launch(void* const* d_in, const int* in_sizes, int n_in,
                              void* d_out, int out_size, void* d_ws, size_t ws_size,
                              hipStream_t stream) {
    const float* x = (const float*)d_in[0];
    float* out = (float*)d_out;
    const int B = in_sizes[0] / D_DIM;  // 65536
    tohypersphere_kernel<<<B / ROWS, TPB, 0, stream>>>(x, out);
}

// Round 7
// 412.104 us; speedup vs baseline: 1.0535x; 1.0337x over previous
//
#include <hip/hip_runtime.h>
#include <math.h>

// ToHyperSphere: x (B=65536, D=1024) fp32 -> out (B, D) fp32
// out[0]   = sqrt(sum x^2)                        (r)
// out[j]   = acos(x[j-1]/suffix_norm[j-1]), j=1..D-2
// out[D-1] = x[D-1] < 0 ? 2pi - phi[D-2] : phi[D-2]
// suffix_norm[j] = sqrt(sum_{k>=j} x[k]^2)
//
// ROUND-7: EXACTLY the R4 kernel (best structure: block-per-row,
// 1 float4/thread, DPP suffix scan, poly acos) with ONE change:
// nontemporal output stores.
//  - R4's stores are full-line contiguous (1KB/wave/instruction), so nt
//    (no-allocate) writes are full-line streaming -- R1's NT disaster was
//    caused by its 64B-strided layout (partial-line RMW), not by nt itself.
//  - mechanism: output write-allocate was inserting 256MB/iter into the
//    256MB Infinity Cache, evicting the input between graph replays
//    (measured FETCH ~134MB = half the input re-fetched from HBM each
//    iter). nt stores leave the input L3-resident -> read stream comes
//    from L3, HBM sees mostly the 268MB write stream.
// Structural notes from failed rounds: persistent blocks regress (R5),
// ROWS=2 per block regresses (R6), VALU cuts are neutral (R4 vs R0) --
// the kernel is memory-system-bound, not VALU/scan/barrier-bound.

#define D_DIM 1024
#define TPB 256  // 4 waves per block, one block per row

typedef float v4f __attribute__((ext_vector_type(4)));

// DPP: value of (lane + N) within the 16-lane row, 0 past row end.
template <int CTRL>
__device__ __forceinline__ float dpp0(float x) {
    return __builtin_bit_cast(
        float, __builtin_amdgcn_update_dpp(0, __builtin_bit_cast(int, x),
                                           CTRL, 0xF, 0xF, true));
}

__device__ __forceinline__ float rdlane(float x, int l) {
    return __builtin_bit_cast(
        float, __builtin_amdgcn_readlane(__builtin_bit_cast(int, x), l));
}

// acos via Abramowitz&Stegun 4.4.46: acos(a) = sqrt(1-a)*poly(a), a in [0,1];
// acos(x) = pi - acos(-x) for x < 0.
__device__ __forceinline__ float fast_acos(float x) {
    float a = fabsf(x);
    float p = fmaf(a, -0.0012624911f, 0.0066700901f);
    p = fmaf(p, a, -0.0170881256f);
    p = fmaf(p, a, 0.0308918810f);
    p = fmaf(p, a, -0.0501743046f);
    p = fmaf(p, a, 0.0889789874f);
    p = fmaf(p, a, -0.2145988016f);
    p = fmaf(p, a, 1.5707963050f);
    float r = sqrtf(1.0f - a) * p;
    return x < 0.0f ? 3.14159274101257f - r : r;
}

__device__ __forceinline__ float ang(float num, float den) {
    float r = num * rsqrtf(den);
    r = fminf(1.0f, fmaxf(-1.0f, r));
    return fast_acos(r);
}

__global__ __launch_bounds__(TPB) void tohypersphere_kernel(
    const float* __restrict__ x, float* __restrict__ out) {
    const int t = threadIdx.x;
    const int lane = t & 63;
    const int wave = t >> 6;
    const int r16 = lane >> 4;
    const size_t row_off = (size_t)blockIdx.x * D_DIM;

    const float4 v = ((const float4*)(x + row_off))[t];

    // thread-local suffix sums of squares (elements 4t..4t+3)
    const float s3 = v.w * v.w;
    const float s2 = fmaf(v.z, v.z, s3);
    const float s1 = fmaf(v.y, v.y, s2);
    const float s0 = fmaf(v.x, v.x, s1);

    // 16-lane-row inclusive suffix scan of s0 (unguarded DPP adds)
    float ts = s0;
    ts += dpp0<0x101>(ts);  // row_shl:1
    ts += dpp0<0x102>(ts);  // row_shl:2
    ts += dpp0<0x104>(ts);  // row_shl:4
    ts += dpp0<0x108>(ts);  // row_shl:8

    // row totals live at lanes 0,16,32,48 -> wave-uniform scalars
    const float R0 = rdlane(ts, 0);
    const float R1 = rdlane(ts, 16);
    const float R2 = rdlane(ts, 32);
    const float R3 = rdlane(ts, 48);

    // inclusive suffix within the wave
    float after_rows = 0.0f;
    if (r16 < 1) after_rows += R1;
    if (r16 < 2) after_rows += R2;
    if (r16 < 3) after_rows += R3;
    const float incl_wave = ts + after_rows;
    const float wtot = (R0 + R1) + (R2 + R3);  // wave total (uniform)

    __shared__ float wave_tot[4];  // per-wave sum of squares
    __shared__ float edge_xw[4];   // last element (v.w) of each wave
    if (lane == 0) wave_tot[wave] = wtot;
    if (lane == 63) edge_xw[wave] = v.w;

    // previous thread's last element x[4t-1] (intra-wave part, pre-barrier)
    float xw_prev = __shfl_up(v.w, 1, 64);

    __syncthreads();

    float after_waves = 0.0f;
#pragma unroll
    for (int w = 1; w < 4; ++w)
        if (w > wave) after_waves += wave_tot[w];
    if (lane == 0 && wave > 0) xw_prev = edge_xw[wave - 1];

    const float incl = incl_wave + after_waves;  // suffix[4t]
    const float excl = incl - s0;                // suffix strictly after 4t+3

    float o0, o1, o2, o3;
    o1 = ang(v.x, incl);       // phi[4t]   -> out[4t+1]
    o2 = ang(v.y, s1 + excl);  // phi[4t+1] -> out[4t+2]
    o3 = ang(v.z, s2 + excl);  // phi[4t+2] -> out[4t+3]
    if (t == 0) {
        o0 = sqrtf(incl);      // r -> out[0]
    } else {
        // phi[4t-1]: suffix[4t-1] = x[4t-1]^2 + suffix[4t]
        o0 = ang(xw_prev, fmaf(xw_prev, xw_prev, incl));
    }
    if (t == TPB - 1 && v.w < 0.0f) {
        // out[D-1]: sign-adjusted phi[D-2]
        o3 = 6.283185307179586476f - o3;
    }

    v4f tv = {o0, o1, o2, o3};
    __builtin_nontemporal_store(tv, (v4f*)(out + row_off) + t);
}

extern "C" void kernel_launch(void* const* d_in, const int* in_sizes, int n_in,
                              void* d_out, int out_size, void* d_ws, size_t ws_size,
                              hipStream_t stream) {
    const float* x = (const float*)d_in[0];
    float* out = (float*)d_out;
    const int B = in_sizes[0] / D_DIM;  // 65536
    tohypersphere_kernel<<<B, TPB, 0, stream>>>(x, out);
}